// Round 4
// baseline (213.796 us; speedup 1.0000x reference)
//
#include <hip/hip_runtime.h>
#include <stdint.h>

// ---------- types / helpers ----------
typedef short bf16x8 __attribute__((ext_vector_type(8)));
typedef float f32x4 __attribute__((ext_vector_type(4)));

#define MFMA_BF16(a, b, c) __builtin_amdgcn_mfma_f32_16x16x32_bf16((a), (b), (c), 0, 0, 0)

__device__ __forceinline__ short f2bf(float x) {
  union { float f; uint32_t u; } v; v.f = x;
  uint32_t r = (v.u + 0x7FFFu + ((v.u >> 16) & 1u)) >> 16;  // RNE
  return (short)r;
}
__device__ __forceinline__ uint32_t rnd_bf_hi(float x) {  // rounded bits, bf16 in high half
  union { float f; uint32_t u; } v; v.f = x;
  return v.u + 0x7FFFu + ((v.u >> 16) & 1u);
}
__device__ __forceinline__ uint32_t pack2bf(float a, float b) {
  // D = [bf16(b) : bf16(a)]  via byte-select
  return __builtin_amdgcn_perm(rnd_bf_hi(b), rnd_bf_hi(a), 0x07060302);
}
__device__ __forceinline__ float bfbits2f(uint32_t b16) {
  union { uint32_t u; float f; } v; v.u = b16 << 16; return v.f;
}
__device__ __forceinline__ float fexp2(float x) {
#if __has_builtin(__builtin_amdgcn_exp2f)
  return __builtin_amdgcn_exp2f(x);
#else
  return __expf(x * 0.6931471805599453f);
#endif
}
__device__ __forceinline__ void async16(const void* g, void* l) {
  __builtin_amdgcn_global_load_lds(
      (const __attribute__((address_space(1))) uint32_t*)g,
      (__attribute__((address_space(3))) uint32_t*)l, 16, 0, 0);
}

#define BAR() __builtin_amdgcn_s_barrier()
#define LGKM0() asm volatile("s_waitcnt lgkmcnt(0)" ::: "memory")
#define VMCNT(n) asm volatile("s_waitcnt vmcnt(" #n ")" ::: "memory")
#define PRIO1() __builtin_amdgcn_s_setprio(1)
#define PRIO0() __builtin_amdgcn_s_setprio(0)

// ---------- prep: fused fp32->bf16 casts + gates context GEMV ----------
__global__ __launch_bounds__(256) void prep_k(
    const float* __restrict__ x, const float* __restrict__ Wq,
    const float* __restrict__ Wk, const float* __restrict__ Wv,
    const float* __restrict__ Wo, const float* __restrict__ bq,
    short* __restrict__ xb, short* __restrict__ Wqb, short* __restrict__ Wkb,
    short* __restrict__ Wvb, short* __restrict__ Wob, float* __restrict__ ctx) {
  __shared__ float xs[1024];
  const int bid = blockIdx.x;
  const int tid = threadIdx.x;
  if (bid < 8192) {
    const float* src; short* dst; int idx;
    if (bid < 4096) {
      src = x; dst = xb; idx = (bid << 8) + tid;
    } else {
      const int r = bid - 4096;
      const int z = r >> 10;
      src = (z == 0) ? Wq : (z == 1) ? Wk : (z == 2) ? Wv : Wo;
      dst = (z == 0) ? Wqb : (z == 1) ? Wkb : (z == 2) ? Wvb : Wob;
      idx = ((r & 1023) << 8) + tid;
    }
    float4 v = ((const float4*)src)[idx];
    short4 o;
    o.x = f2bf(v.x); o.y = f2bf(v.y); o.z = f2bf(v.z); o.w = f2bf(v.w);
    ((short4*)dst)[idx] = o;
  } else {
    // gates context: ctx[b][n] = x[b,0,:] . Wq[n,:] + bq[n]   (fp32 exact path)
    const int r = bid - 8192;
    const int b = r >> 4;
    const int n0 = (r & 15) << 6;
    for (int i = tid; i < 1024; i += 256) xs[i] = x[b * 1048576 + i];
    __syncthreads();
    const int w = tid >> 6, lane = tid & 63;
    const float4* xv4 = (const float4*)xs;
    for (int rr = 0; rr < 16; ++rr) {
      const int n = n0 + (w << 4) + rr;
      const float4* wrow = (const float4*)(Wq + n * 1024);
      float p = 0.f;
#pragma unroll
      for (int c2 = 0; c2 < 4; ++c2) {
        float4 wv = wrow[lane + (c2 << 6)];
        float4 xv = xv4[lane + (c2 << 6)];
        p += xv.x * wv.x + xv.y * wv.y + xv.z * wv.z + xv.w * wv.w;
      }
#pragma unroll
      for (int off = 32; off; off >>= 1) p += __shfl_xor(p, off);
      if (lane == 0) ctx[b * 1024 + n] = p + bq[n];
    }
  }
}

// ---------- gates finisher: c, scale*log2e, u ----------
__global__ __launch_bounds__(256) void gates_fin(const float* __restrict__ ctx,
                                                 const float* __restrict__ Wg1,
                                                 const float* __restrict__ bg1,
                                                 const float* __restrict__ Wg2,
                                                 const float* __restrict__ bg2,
                                                 float* __restrict__ gates,
                                                 float* __restrict__ u_out) {
  __shared__ float red[16];
  const int tid = threadIdx.x, w = tid >> 6, lane = tid & 63;
  for (int b = 0; b < 4; ++b) {
    float4 cv = ((const float4*)(ctx + b * 1024))[tid];
    float4 w1 = ((const float4*)Wg1)[tid];
    float4 w2 = ((const float4*)Wg2)[tid];
    float p1 = cv.x * w1.x + cv.y * w1.y + cv.z * w1.z + cv.w * w1.w;
    float p2 = cv.x * w2.x + cv.y * w2.y + cv.z * w2.z + cv.w * w2.w;
#pragma unroll
    for (int off = 32; off; off >>= 1) { p1 += __shfl_xor(p1, off); p2 += __shfl_xor(p2, off); }
    if (lane == 0) { red[w] = p1; red[8 + w] = p2; }
    __syncthreads();
    if (tid == 0) {
      float g1 = red[0] + red[1] + red[2] + red[3] + bg1[0];
      float g2 = red[8] + red[9] + red[10] + red[11] + bg2[0];
      float q1 = 1.f / (1.f + expf(-g1));
      float q2 = 1.f / (1.f + expf(-g2));
      float c = fminf(fmaxf(q1 * q2, 1e-8f), 1.0f);
      gates[b * 2 + 0] = c;
      gates[b * 2 + 1] = (c < 0.3f ? c : 1.0f) * 0.125f * 1.4426950408889634f;
      u_out[b] = 1.0f - c;
    }
    __syncthreads();
  }
}

// ---------- fused QKV GEMM: 256x256 8-phase template (T1..T5) ----------
// LDS swizzle = m201 st_16x32: 16B-chunk-bit-1 ^= row-bit-2 (byte^=((byte>>9)&1)<<5).
// Applied both-sides: inverse-swizzled global source (stage) + swizzled RD.
template <bool SWP>
__device__ __forceinline__ void qkv_core(const short* __restrict__ xb,
                                         const short* __restrict__ W,
                                         const float* __restrict__ bias,
                                         short* __restrict__ out,
                                         short* sm, int m0, int nl0) {
  const int tid = threadIdx.x;
  const int wid = tid >> 6, lane = tid & 63;
  const int wr = wid >> 2, wc = wid & 3;
  const int m15 = lane & 15, quad = lane >> 4;

  // staging: linear LDS chunk (rowb, tid&7) holds logical k-chunk (tid&7)^((rowb>>2&1)<<1)
  const int rowb = tid >> 3;
  const int c16 = (tid & 7) ^ (((tid >> 5) & 1) << 1);  // rowb>>2 == tid>>5
  const short* aB = xb + (m0 + rowb) * 1024 + (c16 << 3);
  const short* bB = W + (nl0 + rowb) * 1024 + (c16 << 3);

  short* As = sm;           // [2][16384] shorts
  short* Bs = sm + 32768;   // [2][16384] shorts

#define STAGEH(sb, tt, hf, dst)                        \
  do {                                                 \
    const short* _s = (sb) + (hf)*131072 + (tt)*64;    \
    short* _d = (dst) + ((hf) << 13) + (tid << 3);     \
    async16(_s, _d);                                   \
    async16(_s + 65536, _d + 4096);                    \
  } while (0)

#define RD(base, f, kk)                                                        \
  (*(const bf16x8*)((base) + ((f) << 10) + (m15 << 6) +                        \
                    (((((kk) << 2) + quad) ^ ((m15 & 4) >> 1)) << 3)))

#define MM(accr, af, bf)                                   \
  do {                                                     \
    if (SWP) accr = MFMA_BF16((bf), (af), (accr));         \
    else     accr = MFMA_BF16((af), (bf), (accr));         \
  } while (0)

  f32x4 acc[8][4];
#pragma unroll
  for (int i = 0; i < 8; ++i)
#pragma unroll
    for (int j = 0; j < 4; ++j) { f32x4 zz = {0.f, 0.f, 0.f, 0.f}; acc[i][j] = zz; }

  STAGEH(bB, 0, 0, Bs);
  STAGEH(aB, 0, 0, As);
  STAGEH(aB, 0, 1, As);
  STAGEH(bB, 0, 1, Bs);
  STAGEH(bB, 1, 0, Bs + 16384);
  STAGEH(aB, 1, 0, As + 16384);
  VMCNT(4);
  BAR();

  bf16x8 a[4][2], b0[2][2], b1[2][2];

  for (int t = 0; t < 16; ++t) {
    const int buf = t & 1;
    const short* Ab = As + (buf << 14) + (wr << 13);
    const short* Bb = Bs + (buf << 14) + ((wc >> 1) << 13) + ((wc & 1) << 12);
    short* Adn = As + ((buf ^ 1) << 14);
    short* Bdn = Bs + ((buf ^ 1) << 14);
    short* Ad2 = As + (buf << 14);
    short* Bd2 = Bs + (buf << 14);

#pragma unroll
    for (int fi = 0; fi < 4; ++fi) { a[fi][0] = RD(Ab, fi, 0); a[fi][1] = RD(Ab, fi, 1); }
#pragma unroll
    for (int fj = 0; fj < 2; ++fj) { b0[fj][0] = RD(Bb, fj, 0); b0[fj][1] = RD(Bb, fj, 1); }
    if (t < 15) STAGEH(aB, t + 1, 1, Adn);
    BAR();
    LGKM0();
    PRIO1();
#pragma unroll
    for (int fi = 0; fi < 4; ++fi)
#pragma unroll
      for (int fj = 0; fj < 2; ++fj) {
        MM(acc[fi][fj], a[fi][0], b0[fj][0]);
        MM(acc[fi][fj], a[fi][1], b0[fj][1]);
      }
    PRIO0();
    BAR();

#pragma unroll
    for (int fj = 0; fj < 2; ++fj) { b1[fj][0] = RD(Bb, 2 + fj, 0); b1[fj][1] = RD(Bb, 2 + fj, 1); }
    if (t < 15) STAGEH(bB, t + 1, 1, Bdn);
    BAR();
    LGKM0();
    PRIO1();
#pragma unroll
    for (int fi = 0; fi < 4; ++fi)
#pragma unroll
      for (int fj = 0; fj < 2; ++fj) {
        MM(acc[fi][2 + fj], a[fi][0], b1[fj][0]);
        MM(acc[fi][2 + fj], a[fi][1], b1[fj][1]);
      }
    PRIO0();
    BAR();

#pragma unroll
    for (int fi = 0; fi < 4; ++fi) { a[fi][0] = RD(Ab, 4 + fi, 0); a[fi][1] = RD(Ab, 4 + fi, 1); }
    if (t < 14) STAGEH(bB, t + 2, 0, Bd2);
    BAR();
    LGKM0();
    PRIO1();
#pragma unroll
    for (int fi = 0; fi < 4; ++fi)
#pragma unroll
      for (int fj = 0; fj < 2; ++fj) {
        MM(acc[4 + fi][2 + fj], a[fi][0], b1[fj][0]);
        MM(acc[4 + fi][2 + fj], a[fi][1], b1[fj][1]);
      }
    PRIO0();
    BAR();

    if (t < 14) STAGEH(aB, t + 2, 0, Ad2);
    BAR();
    PRIO1();
#pragma unroll
    for (int fi = 0; fi < 4; ++fi)
#pragma unroll
      for (int fj = 0; fj < 2; ++fj) {
        MM(acc[4 + fi][fj], a[fi][0], b0[fj][0]);
        MM(acc[4 + fi][fj], a[fi][1], b0[fj][1]);
      }
    PRIO0();
    if (t < 14) { VMCNT(4); }
    else if (t == 14) { VMCNT(0); }
    BAR();
  }

  const int nw = nl0 + (wc << 6);
  if (SWP) {
#pragma unroll
    for (int fj = 0; fj < 4; ++fj) {
      const int n = nw + (fj << 4) + (quad << 2);
      const float4 bv = *(const float4*)(bias + n);
      const int hh = n >> 6, dk0 = n & 63;
#pragma unroll
      for (int fi = 0; fi < 8; ++fi) {
        const int m = m0 + (wr << 7) + (fi << 4) + m15;
        const int bb = m >> 10, tt = m & 1023;
        uint2 st;
        st.x = pack2bf(acc[fi][fj][0] + bv.x, acc[fi][fj][1] + bv.y);
        st.y = pack2bf(acc[fi][fj][2] + bv.z, acc[fi][fj][3] + bv.w);
        *(uint2*)(out + (((bb << 4) + hh) << 16) + (tt << 6) + dk0) = st;
      }
    }
  } else {
#pragma unroll
    for (int fj = 0; fj < 4; ++fj) {
      const int n = nw + (fj << 4) + m15;
      const float bv = bias[n];
      const int hh = n >> 6, dk = n & 63;
#pragma unroll
      for (int fi = 0; fi < 8; ++fi) {
        const int m = m0 + (wr << 7) + (fi << 4) + (quad << 2);
        const int bb = m >> 10, t0 = m & 1023;
        uint2 st;
        st.x = pack2bf(acc[fi][fj][0] + bv, acc[fi][fj][1] + bv);
        st.y = pack2bf(acc[fi][fj][2] + bv, acc[fi][fj][3] + bv);
        *(uint2*)(out + (((bb << 4) + hh) << 16) + (dk << 10) + t0) = st;
      }
    }
  }
#undef STAGEH
#undef RD
#undef MM
}

__global__ __launch_bounds__(512) void gemm_qkv8(
    const short* __restrict__ xb,
    const short* __restrict__ Wqb, const short* __restrict__ Wkb, const short* __restrict__ Wvb,
    const float* __restrict__ bq, const float* __restrict__ bk, const float* __restrict__ bv,
    short* __restrict__ Qh, short* __restrict__ Kh, short* __restrict__ Vt) {
  const int lin = blockIdx.x;
  const int s = ((lin & 7) * 24) + (lin >> 3);
  const int bx = s & 15, by = s >> 4;
  const int z = by >> 2;
  const int m0 = bx << 8, nl0 = (by & 3) << 8;
  extern __shared__ short sm[];
  if (z == 0)      qkv_core<true >(xb, Wqb, bq, Qh, sm, m0, nl0);
  else if (z == 1) qkv_core<true >(xb, Wkb, bk, Kh, sm, m0, nl0);
  else             qkv_core<false>(xb, Wvb, bv, Vt, sm, m0, nl0);
}

// ---------- output projection GEMM: 128x128, R0-verified 2-barrier, fp32 out ----------
__global__ __launch_bounds__(256) void gemm_out(const short* __restrict__ Ab,
                                                const short* __restrict__ Wo,
                                                const float* __restrict__ bo,
                                                float* __restrict__ Cout) {
  const int m0 = blockIdx.x << 7;
  const int n0 = blockIdx.y << 7;
  const int tid = threadIdx.x;
  const int w = tid >> 6, lane = tid & 63;
  const int m15 = lane & 15, quad = lane >> 4;
  const int wr = w >> 1, wc = w & 1;

  __shared__ short As[4096];
  __shared__ short Bs[4096];

  f32x4 acc[4][4];
#pragma unroll
  for (int i = 0; i < 4; ++i)
#pragma unroll
    for (int j = 0; j < 4; ++j) { f32x4 zz = {0.f, 0.f, 0.f, 0.f}; acc[i][j] = zz; }

  const int srow = (w << 5) + (lane >> 2);
  const int scol = (lane & 3) << 3;
  const short* ga0 = Ab + (m0 + srow) * 1024 + scol;
  const short* ga1 = ga0 + 16 * 1024;
  const short* gb0 = Wo + (n0 + srow) * 1024 + scol;
  const short* gb1 = gb0 + 16 * 1024;
  short* la0 = &As[srow * 32 + scol];
  short* la1 = la0 + 512;
  short* lb0 = &Bs[srow * 32 + scol];
  short* lb1 = lb0 + 512;

  for (int kt = 0; kt < 32; ++kt) {
    async16(ga0, la0); async16(ga1, la1);
    async16(gb0, lb0); async16(gb1, lb1);
    ga0 += 32; ga1 += 32; gb0 += 32; gb1 += 32;
    __syncthreads();
    bf16x8 a[4], b[4];
#pragma unroll
    for (int i = 0; i < 4; ++i)
      a[i] = *(const bf16x8*)(&As[((wr << 6) + (i << 4) + m15) * 32 + (quad << 3)]);
#pragma unroll
    for (int j = 0; j < 4; ++j)
      b[j] = *(const bf16x8*)(&Bs[((wc << 6) + (j << 4) + m15) * 32 + (quad << 3)]);
#pragma unroll
    for (int i = 0; i < 4; ++i)
#pragma unroll
      for (int j = 0; j < 4; ++j)
        acc[i][j] = MFMA_BF16(a[i], b[j], acc[i][j]);
    __syncthreads();
  }

#pragma unroll
  for (int j = 0; j < 4; ++j) {
    const int n = n0 + (wc << 6) + (j << 4) + m15;
    const float bb_ = bo[n];
#pragma unroll
    for (int i = 0; i < 4; ++i) {
      const int mb = m0 + (wr << 6) + (i << 4) + (quad << 2);
#pragma unroll
      for (int r = 0; r < 4; ++r)
        Cout[(mb + r) * 1024 + n] = acc[i][j][r] + bb_;
    }
  }
}

// ---------- flash attention, transposed-S, QBLK=128, fused meanV (ones-MFMA) ----------
// Per block: 128 q-rows, 4 waves; wave w owns qA = q0+w*16 and qB = qA+64.
// meanV fused: o_mv[jd] += MFMA(v, ones) -> every C column = sum_t V^T[d][t],
// exactly o_acc's register layout, so the finisher consumes it directly.
__global__ __launch_bounds__(256, 2) void attn_k(const short* __restrict__ Qh,
                                                 const short* __restrict__ Kh,
                                                 const short* __restrict__ Vt,
                                                 const float* __restrict__ gates,
                                                 short* __restrict__ attnb) {
  const int bh = blockIdx.x;
  const int b = bh >> 4, h = bh & 15;
  const int q0 = blockIdx.y << 7;
  const int tid = threadIdx.x;
  const int w = tid >> 6, lane = tid & 63;
  const int m15 = lane & 15, quad = lane >> 4;

  __shared__ short Ks[2][4096];  // [64 k][64 d], 8-short chunks XOR-swizzled by row&7
  __shared__ short Vs[2][4096];  // [64 d][64 t], same swizzle

  const short* ksrc = Kh + bh * 65536;
  const short* vsrc = Vt + bh * 65536;

  const float sl = gates[b * 2 + 1];

  // hoisted Q B-fragments for both q-groups (loop-invariant)
  const short* qsrcA = Qh + ((bh << 10) + q0 + (w << 4) + m15) * 64;
  const short* qsrcB = qsrcA + 64 * 64;  // +64 q-rows
  const bf16x8 qA0 = *(const bf16x8*)(qsrcA + (quad << 3));
  const bf16x8 qA1 = *(const bf16x8*)(qsrcA + 32 + (quad << 3));
  const bf16x8 qB0 = *(const bf16x8*)(qsrcB + (quad << 3));
  const bf16x8 qB1 = *(const bf16x8*)(qsrcB + 32 + (quad << 3));

  const bf16x8 vone = {0x3F80, 0x3F80, 0x3F80, 0x3F80, 0x3F80, 0x3F80, 0x3F80, 0x3F80};

  const int off0 = tid, off1 = tid + 256;
  const int r0 = off0 >> 3, cb0 = (off0 & 7) ^ (r0 & 7);
  const int r1 = off1 >> 3, cb1 = (off1 & 7) ^ (r1 & 7);

#define STAGE(kv, bufi)                                                        \
  do {                                                                         \
    async16(ksrc + (((kv) << 6) + r0) * 64 + (cb0 << 3), &Ks[bufi][off0 << 3]);\
    async16(ksrc + (((kv) << 6) + r1) * 64 + (cb1 << 3), &Ks[bufi][off1 << 3]);\
    async16(vsrc + r0 * 1024 + ((kv) << 6) + (cb0 << 3), &Vs[bufi][off0 << 3]);\
    async16(vsrc + r1 * 1024 + ((kv) << 6) + (cb1 << 3), &Vs[bufi][off1 << 3]);\
  } while (0)

  STAGE(0, 0);

  float lsumA = 0.f, lsumB = 0.f;
  f32x4 oA[4], oB[4], o_mv[4];
#pragma unroll
  for (int jd = 0; jd < 4; ++jd) {
    f32x4 zz = {0.f, 0.f, 0.f, 0.f};
    oA[jd] = zz; oB[jd] = zz; o_mv[jd] = zz;
  }

  const int srcA = ((quad & 1) << 5) + m15;
  const int srcB = srcA + 16;
  const bool selhi = (quad & 2) != 0;

#define BUILD_PF(pf, pk)                                                       \
  do {                                                                         \
    _Pragma("unroll")                                                          \
    for (int Hh = 0; Hh < 2; ++Hh) {                                           \
      uint32_t f[4];                                                           \
      _Pragma("unroll")                                                        \
      for (int rp = 0; rp < 2; ++rp) {                                         \
        uint32_t alo = (uint32_t)__shfl((int)pk[2 * Hh][rp], srcA);            \
        uint32_t ahi = (uint32_t)__shfl((int)pk[2 * Hh + 1][rp], srcA);        \
        uint32_t blo = (uint32_t)__shfl((int)pk[2 * Hh][rp], srcB);            \
        uint32_t bhi = (uint32_t)__shfl((int)pk[2 * Hh + 1][rp], srcB);        \
        f[rp]     = selhi ? ahi : alo;                                         \
        f[2 + rp] = selhi ? bhi : blo;                                         \
      }                                                                        \
      pf[Hh] = *(bf16x8*)f;                                                    \
    }                                                                          \
  } while (0)

  for (int kv = 0; kv < 16; ++kv) {
    __syncthreads();  // drains STAGE(kv) (vmcnt) and prior iter's frag reads
    if (kv < 15) STAGE(kv + 1, (kv + 1) & 1);
    const short* Kb = &Ks[kv & 1][0];
    const short* Vb = &Vs[kv & 1][0];

    // S^T tiles for both q-groups; K frags shared
    f32x4 sA[4], sB[4];
#pragma unroll
    for (int s = 0; s < 4; ++s) {
      const int row = (s << 4) + m15;
      const int sw = row & 7;
      bf16x8 a0 = *(const bf16x8*)(Kb + (row << 6) + ((quad ^ sw) << 3));
      bf16x8 a1 = *(const bf16x8*)(Kb + (row << 6) + (((quad + 4) ^ sw) << 3));
      f32x4 zA = {0.f, 0.f, 0.f, 0.f};
      zA = MFMA_BF16(a0, qA0, zA);
      zA = MFMA_BF16(a1, qA1, zA);
      sA[s] = zA;
      f32x4 zB = {0.f, 0.f, 0.f, 0.f};
      zB = MFMA_BF16(a0, qB0, zB);
      zB = MFMA_BF16(a1, qB1, zB);
      sB[s] = zB;
    }

    // lane-local softmax numerators + packed bf16 pairs (both chains)
    uint32_t pkA[4][2], pkB[4][2];
#pragma unroll
    for (int s = 0; s < 4; ++s) {
      float a0 = fexp2(sA[s][0] * sl);
      float a1 = fexp2(sA[s][1] * sl);
      float a2 = fexp2(sA[s][2] * sl);
      float a3 = fexp2(sA[s][3] * sl);
      lsumA += (a0 + a1) + (a2 + a3);
      pkA[s][0] = pack2bf(a0, a1);
      pkA[s][1] = pack2bf(a2, a3);
      float b0 = fexp2(sB[s][0] * sl);
      float b1 = fexp2(sB[s][1] * sl);
      float b2 = fexp2(sB[s][2] * sl);
      float b3 = fexp2(sB[s][3] * sl);
      lsumB += (b0 + b1) + (b2 + b3);
      pkB[s][0] = pack2bf(b0, b1);
      pkB[s][1] = pack2bf(b2, b3);
    }

    bf16x8 pfA[2], pfB[2];
    BUILD_PF(pfA, pkA);
    BUILD_PF(pfB, pkB);

    // O^T += V^T * P for both chains; V frags shared; meanV via ones-MFMA
#pragma unroll
    for (int jd = 0; jd < 4; ++jd) {
      const int row = (jd << 4) + m15;
      const int sw = row & 7;
      bf16x8 v0 = *(const bf16x8*)(Vb + (row << 6) + ((quad ^ sw) << 3));
      bf16x8 v1 = *(const bf16x8*)(Vb + (row << 6) + (((quad + 4) ^ sw) << 3));
      oA[jd] = MFMA_BF16(v0, pfA[0], oA[jd]);
      oA[jd] = MFMA_BF16(v1, pfA[1], oA[jd]);
      oB[jd] = MFMA_BF16(v0, pfB[0], oB[jd]);
      oB[jd] = MFMA_BF16(v1, pfB[1], oB[jd]);
      o_mv[jd] = MFMA_BF16(v0, vone, o_mv[jd]);
      o_mv[jd] = MFMA_BF16(v1, vone, o_mv[jd]);
    }
  }
#undef STAGE
#undef BUILD_PF

  // finish l(q): reduce quad partials
  float lA = lsumA;
  lA += __shfl_xor(lA, 16);
  lA += __shfl_xor(lA, 32);
  float lB = lsumB;
  lB += __shfl_xor(lB, 16);
  lB += __shfl_xor(lB, 32);

  const float cg = gates[b * 2 + 0];
  const float sc0A = cg / lA;
  const float sc0B = cg / lB;
  const float coef = (1.0f - cg) * (1.0f / 1024.0f);  // o_mv holds raw sums over t
  const int qrowA = q0 + (w << 4) + m15;
  short* orowA = attnb + ((b << 10) + qrowA) * 1024 + (h << 6);
  short* orowB = orowA + 64 * 1024;  // qrowB = qrowA + 64
#pragma unroll
  for (int jd = 0; jd < 4; ++jd) {
    uint2 stA;
    stA.x = pack2bf(sc0A * oA[jd][0] + coef * o_mv[jd][0],
                    sc0A * oA[jd][1] + coef * o_mv[jd][1]);
    stA.y = pack2bf(sc0A * oA[jd][2] + coef * o_mv[jd][2],
                    sc0A * oA[jd][3] + coef * o_mv[jd][3]);
    *(uint2*)(orowA + (jd << 4) + (quad << 2)) = stA;
    uint2 stB;
    stB.x = pack2bf(sc0B * oB[jd][0] + coef * o_mv[jd][0],
                    sc0B * oB[jd][1] + coef * o_mv[jd][1]);
    stB.y = pack2bf(sc0B * oB[jd][2] + coef * o_mv[jd][2],
                    sc0B * oB[jd][3] + coef * o_mv[jd][3]);
    *(uint2*)(orowB + (jd << 4) + (quad << 2)) = stB;
  }
}

// ---------- launch ----------
extern "C" void kernel_launch(void* const* d_in, const int* in_sizes, int n_in,
                              void* d_out, int out_size, void* d_ws, size_t ws_size,
                              hipStream_t stream) {
  const float* x   = (const float*)d_in[0];
  const float* Wq  = (const float*)d_in[1];
  const float* bq  = (const float*)d_in[2];
  const float* Wk  = (const float*)d_in[3];
  const float* bk  = (const float*)d_in[4];
  const float* Wv  = (const float*)d_in[5];
  const float* bv  = (const float*)d_in[6];
  const float* Wo  = (const float*)d_in[7];
  const float* bo  = (const float*)d_in[8];
  const float* Wg1 = (const float*)d_in[9];
  const float* bg1 = (const float*)d_in[10];
  const float* Wg2 = (const float*)d_in[11];
  const float* bg2 = (const float*)d_in[12];
  float* out = (float*)d_out;

  char* ws = (char*)d_ws;
  short* xb   = (short*)(ws + 0);          //  8 MB  x bf16 [4096][1024]
  short* Wqb  = (short*)(ws + 8388608);    //  2 MB
  short* Wkb  = (short*)(ws + 10485760);   //  2 MB
  short* Wvb  = (short*)(ws + 12582912);   //  2 MB
  short* Wob  = (short*)(ws + 14680064);   //  2 MB
  short* Qh   = (short*)(ws + 16777216);   //  8 MB  [BH][T][64]
  short* Kh   = (short*)(ws + 25165824);   //  8 MB  [BH][T][64]
  short* Vt   = (short*)(ws + 33554432);   //  8 MB  [BH][64][T]
  short* attb = (short*)(ws + 41943040);   //  8 MB  [4096][1024]
  float* ctx  = (float*)(ws + 50331648);   // 16 KB
  float* gat  = (float*)(ws + 50348032);   // 32 B   [B][{c, scale*log2e}]

  static bool lds_inited = false;
  if (!lds_inited) {
    hipFuncSetAttribute(reinterpret_cast<const void*>(gemm_qkv8),
                        hipFuncAttributeMaxDynamicSharedMemorySize, 131072);
    lds_inited = true;
  }

  prep_k<<<8256, 256, 0, stream>>>(x, Wq, Wk, Wv, Wo, bq,
                                   xb, Wqb, Wkb, Wvb, Wob, ctx);
  gates_fin<<<1, 256, 0, stream>>>(ctx, Wg1, bg1, Wg2, bg2, gat, out + 4194304);

  gemm_qkv8<<<192, 512, 131072, stream>>>(xb, Wqb, Wkb, Wvb, bq, bk, bv,
                                          Qh, Kh, Vt);
  attn_k<<<dim3(64, 8), 256, 0, stream>>>(Qh, Kh, Vt, gat, attb);
  gemm_out<<<dim3(32, 8), 256, 0, stream>>>(attb, Wob, bo, out);
}

// Round 5
// 209.580 us; speedup vs baseline: 1.0201x; 1.0201x over previous
//
#include <hip/hip_runtime.h>
#include <stdint.h>

// ---------- types / helpers ----------
typedef short bf16x8 __attribute__((ext_vector_type(8)));
typedef float f32x4 __attribute__((ext_vector_type(4)));

#define MFMA_BF16(a, b, c) __builtin_amdgcn_mfma_f32_16x16x32_bf16((a), (b), (c), 0, 0, 0)

__device__ __forceinline__ short f2bf(float x) {
  union { float f; uint32_t u; } v; v.f = x;
  uint32_t r = (v.u + 0x7FFFu + ((v.u >> 16) & 1u)) >> 16;  // RNE
  return (short)r;
}
__device__ __forceinline__ uint32_t rnd_bf_hi(float x) {  // rounded bits, bf16 in high half
  union { float f; uint32_t u; } v; v.f = x;
  return v.u + 0x7FFFu + ((v.u >> 16) & 1u);
}
__device__ __forceinline__ uint32_t pack2bf(float a, float b) {
  // D = [bf16(b) : bf16(a)]  via byte-select
  return __builtin_amdgcn_perm(rnd_bf_hi(b), rnd_bf_hi(a), 0x07060302);
}
__device__ __forceinline__ float bfbits2f(uint32_t b16) {
  union { uint32_t u; float f; } v; v.u = b16 << 16; return v.f;
}
__device__ __forceinline__ float fexp2(float x) {
#if __has_builtin(__builtin_amdgcn_exp2f)
  return __builtin_amdgcn_exp2f(x);
#else
  return __expf(x * 0.6931471805599453f);
#endif
}
__device__ __forceinline__ void async16(const void* g, void* l) {
  __builtin_amdgcn_global_load_lds(
      (const __attribute__((address_space(1))) uint32_t*)g,
      (__attribute__((address_space(3))) uint32_t*)l, 16, 0, 0);
}

#define BAR() __builtin_amdgcn_s_barrier()
#define LGKM0() asm volatile("s_waitcnt lgkmcnt(0)" ::: "memory")
#define VMCNT(n) asm volatile("s_waitcnt vmcnt(" #n ")" ::: "memory")
#define PRIO1() __builtin_amdgcn_s_setprio(1)
#define PRIO0() __builtin_amdgcn_s_setprio(0)

// ---------- prep: fused fp32->bf16 casts + gates context GEMV ----------
__global__ __launch_bounds__(256) void prep_k(
    const float* __restrict__ x, const float* __restrict__ Wq,
    const float* __restrict__ Wk, const float* __restrict__ Wv,
    const float* __restrict__ Wo, const float* __restrict__ bq,
    short* __restrict__ xb, short* __restrict__ Wqb, short* __restrict__ Wkb,
    short* __restrict__ Wvb, short* __restrict__ Wob, float* __restrict__ ctx) {
  __shared__ float xs[1024];
  const int bid = blockIdx.x;
  const int tid = threadIdx.x;
  if (bid < 8192) {
    const float* src; short* dst; int idx;
    if (bid < 4096) {
      src = x; dst = xb; idx = (bid << 8) + tid;
    } else {
      const int r = bid - 4096;
      const int z = r >> 10;
      src = (z == 0) ? Wq : (z == 1) ? Wk : (z == 2) ? Wv : Wo;
      dst = (z == 0) ? Wqb : (z == 1) ? Wkb : (z == 2) ? Wvb : Wob;
      idx = ((r & 1023) << 8) + tid;
    }
    float4 v = ((const float4*)src)[idx];
    short4 o;
    o.x = f2bf(v.x); o.y = f2bf(v.y); o.z = f2bf(v.z); o.w = f2bf(v.w);
    ((short4*)dst)[idx] = o;
  } else {
    // gates context: ctx[b][n] = x[b,0,:] . Wq[n,:] + bq[n]   (fp32 exact path)
    const int r = bid - 8192;
    const int b = r >> 4;
    const int n0 = (r & 15) << 6;
    for (int i = tid; i < 1024; i += 256) xs[i] = x[b * 1048576 + i];
    __syncthreads();
    const int w = tid >> 6, lane = tid & 63;
    const float4* xv4 = (const float4*)xs;
    for (int rr = 0; rr < 16; ++rr) {
      const int n = n0 + (w << 4) + rr;
      const float4* wrow = (const float4*)(Wq + n * 1024);
      float p = 0.f;
#pragma unroll
      for (int c2 = 0; c2 < 4; ++c2) {
        float4 wv = wrow[lane + (c2 << 6)];
        float4 xv = xv4[lane + (c2 << 6)];
        p += xv.x * wv.x + xv.y * wv.y + xv.z * wv.z + xv.w * wv.w;
      }
#pragma unroll
      for (int off = 32; off; off >>= 1) p += __shfl_xor(p, off);
      if (lane == 0) ctx[b * 1024 + n] = p + bq[n];
    }
  }
}

// ---------- gates finisher: c, scale*log2e, u ----------
__global__ __launch_bounds__(256) void gates_fin(const float* __restrict__ ctx,
                                                 const float* __restrict__ Wg1,
                                                 const float* __restrict__ bg1,
                                                 const float* __restrict__ Wg2,
                                                 const float* __restrict__ bg2,
                                                 float* __restrict__ gates,
                                                 float* __restrict__ u_out) {
  __shared__ float red[16];
  const int tid = threadIdx.x, w = tid >> 6, lane = tid & 63;
  for (int b = 0; b < 4; ++b) {
    float4 cv = ((const float4*)(ctx + b * 1024))[tid];
    float4 w1 = ((const float4*)Wg1)[tid];
    float4 w2 = ((const float4*)Wg2)[tid];
    float p1 = cv.x * w1.x + cv.y * w1.y + cv.z * w1.z + cv.w * w1.w;
    float p2 = cv.x * w2.x + cv.y * w2.y + cv.z * w2.z + cv.w * w2.w;
#pragma unroll
    for (int off = 32; off; off >>= 1) { p1 += __shfl_xor(p1, off); p2 += __shfl_xor(p2, off); }
    if (lane == 0) { red[w] = p1; red[8 + w] = p2; }
    __syncthreads();
    if (tid == 0) {
      float g1 = red[0] + red[1] + red[2] + red[3] + bg1[0];
      float g2 = red[8] + red[9] + red[10] + red[11] + bg2[0];
      float q1 = 1.f / (1.f + expf(-g1));
      float q2 = 1.f / (1.f + expf(-g2));
      float c = fminf(fmaxf(q1 * q2, 1e-8f), 1.0f);
      gates[b * 2 + 0] = c;
      gates[b * 2 + 1] = (c < 0.3f ? c : 1.0f) * 0.125f * 1.4426950408889634f;
      u_out[b] = 1.0f - c;
    }
    __syncthreads();
  }
}

// ---------- fused QKV GEMM: 256x256 8-phase template ----------
// LDS swizzle: chunk ^= row&7 (full 3-bit XOR) — injective on each 8-lane
// ds_read_b128 scheduling group => conflict-free (R1-verified mapping).
template <bool SWP>
__device__ __forceinline__ void qkv_core(const short* __restrict__ xb,
                                         const short* __restrict__ W,
                                         const float* __restrict__ bias,
                                         short* __restrict__ out,
                                         short* sm, int m0, int nl0) {
  const int tid = threadIdx.x;
  const int wid = tid >> 6, lane = tid & 63;
  const int wr = wid >> 2, wc = wid & 3;
  const int m15 = lane & 15, quad = lane >> 4;
  const int swz = m15 & 7;

  // staging: linear LDS chunk (rowb, tid&7) holds logical k-chunk (tid&7)^(rowb&7)
  const int rowb = tid >> 3;
  const int cs = ((tid & 7) ^ (rowb & 7)) << 3;
  const short* aB = xb + (m0 + rowb) * 1024 + cs;
  const short* bB = W + (nl0 + rowb) * 1024 + cs;

  short* As = sm;           // [2][16384] shorts
  short* Bs = sm + 32768;   // [2][16384] shorts

#define STAGEH(sb, tt, hf, dst)                        \
  do {                                                 \
    const short* _s = (sb) + (hf)*131072 + (tt)*64;    \
    short* _d = (dst) + ((hf) << 13) + (tid << 3);     \
    async16(_s, _d);                                   \
    async16(_s + 65536, _d + 4096);                    \
  } while (0)

#define RD(base, f, kk)                                                        \
  (*(const bf16x8*)((base) + ((f) << 10) + (m15 << 6) +                        \
                    (((((kk) << 2) + quad) ^ swz) << 3)))

#define MM(accr, af, bf)                                   \
  do {                                                     \
    if (SWP) accr = MFMA_BF16((bf), (af), (accr));         \
    else     accr = MFMA_BF16((af), (bf), (accr));         \
  } while (0)

  f32x4 acc[8][4];
#pragma unroll
  for (int i = 0; i < 8; ++i)
#pragma unroll
    for (int j = 0; j < 4; ++j) { f32x4 zz = {0.f, 0.f, 0.f, 0.f}; acc[i][j] = zz; }

  STAGEH(bB, 0, 0, Bs);
  STAGEH(aB, 0, 0, As);
  STAGEH(aB, 0, 1, As);
  STAGEH(bB, 0, 1, Bs);
  STAGEH(bB, 1, 0, Bs + 16384);
  STAGEH(aB, 1, 0, As + 16384);
  VMCNT(4);
  BAR();

  bf16x8 a[4][2], b0[2][2], b1[2][2];

  for (int t = 0; t < 16; ++t) {
    const int buf = t & 1;
    const short* Ab = As + (buf << 14) + (wr << 13);
    const short* Bb = Bs + (buf << 14) + ((wc >> 1) << 13) + ((wc & 1) << 12);
    short* Adn = As + ((buf ^ 1) << 14);
    short* Bdn = Bs + ((buf ^ 1) << 14);
    short* Ad2 = As + (buf << 14);
    short* Bd2 = Bs + (buf << 14);

#pragma unroll
    for (int fi = 0; fi < 4; ++fi) { a[fi][0] = RD(Ab, fi, 0); a[fi][1] = RD(Ab, fi, 1); }
#pragma unroll
    for (int fj = 0; fj < 2; ++fj) { b0[fj][0] = RD(Bb, fj, 0); b0[fj][1] = RD(Bb, fj, 1); }
    if (t < 15) STAGEH(aB, t + 1, 1, Adn);
    BAR();
    LGKM0();
    PRIO1();
#pragma unroll
    for (int fi = 0; fi < 4; ++fi)
#pragma unroll
      for (int fj = 0; fj < 2; ++fj) {
        MM(acc[fi][fj], a[fi][0], b0[fj][0]);
        MM(acc[fi][fj], a[fi][1], b0[fj][1]);
      }
    PRIO0();
    BAR();

#pragma unroll
    for (int fj = 0; fj < 2; ++fj) { b1[fj][0] = RD(Bb, 2 + fj, 0); b1[fj][1] = RD(Bb, 2 + fj, 1); }
    if (t < 15) STAGEH(bB, t + 1, 1, Bdn);
    BAR();
    LGKM0();
    PRIO1();
#pragma unroll
    for (int fi = 0; fi < 4; ++fi)
#pragma unroll
      for (int fj = 0; fj < 2; ++fj) {
        MM(acc[fi][2 + fj], a[fi][0], b1[fj][0]);
        MM(acc[fi][2 + fj], a[fi][1], b1[fj][1]);
      }
    PRIO0();
    BAR();

#pragma unroll
    for (int fi = 0; fi < 4; ++fi) { a[fi][0] = RD(Ab, 4 + fi, 0); a[fi][1] = RD(Ab, 4 + fi, 1); }
    if (t < 14) STAGEH(bB, t + 2, 0, Bd2);
    BAR();
    LGKM0();
    PRIO1();
#pragma unroll
    for (int fi = 0; fi < 4; ++fi)
#pragma unroll
      for (int fj = 0; fj < 2; ++fj) {
        MM(acc[4 + fi][2 + fj], a[fi][0], b1[fj][0]);
        MM(acc[4 + fi][2 + fj], a[fi][1], b1[fj][1]);
      }
    PRIO0();
    BAR();

    if (t < 14) STAGEH(aB, t + 2, 0, Ad2);
    BAR();
    PRIO1();
#pragma unroll
    for (int fi = 0; fi < 4; ++fi)
#pragma unroll
      for (int fj = 0; fj < 2; ++fj) {
        MM(acc[4 + fi][fj], a[fi][0], b0[fj][0]);
        MM(acc[4 + fi][fj], a[fi][1], b0[fj][1]);
      }
    PRIO0();
    if (t < 14) { VMCNT(4); }
    else if (t == 14) { VMCNT(0); }
    BAR();
  }

  const int nw = nl0 + (wc << 6);
  if (SWP) {
#pragma unroll
    for (int fj = 0; fj < 4; ++fj) {
      const int n = nw + (fj << 4) + (quad << 2);
      const float4 bv = *(const float4*)(bias + n);
      const int hh = n >> 6, dk0 = n & 63;
#pragma unroll
      for (int fi = 0; fi < 8; ++fi) {
        const int m = m0 + (wr << 7) + (fi << 4) + m15;
        const int bb = m >> 10, tt = m & 1023;
        uint2 st;
        st.x = pack2bf(acc[fi][fj][0] + bv.x, acc[fi][fj][1] + bv.y);
        st.y = pack2bf(acc[fi][fj][2] + bv.z, acc[fi][fj][3] + bv.w);
        *(uint2*)(out + (((bb << 4) + hh) << 16) + (tt << 6) + dk0) = st;
      }
    }
  } else {
#pragma unroll
    for (int fj = 0; fj < 4; ++fj) {
      const int n = nw + (fj << 4) + m15;
      const float bv = bias[n];
      const int hh = n >> 6, dk = n & 63;
#pragma unroll
      for (int fi = 0; fi < 8; ++fi) {
        const int m = m0 + (wr << 7) + (fi << 4) + (quad << 2);
        const int bb = m >> 10, t0 = m & 1023;
        uint2 st;
        st.x = pack2bf(acc[fi][fj][0] + bv, acc[fi][fj][1] + bv);
        st.y = pack2bf(acc[fi][fj][2] + bv, acc[fi][fj][3] + bv);
        *(uint2*)(out + (((bb << 4) + hh) << 16) + (dk << 10) + t0) = st;
      }
    }
  }
#undef STAGEH
#undef RD
#undef MM
}

__global__ __launch_bounds__(512) void gemm_qkv8(
    const short* __restrict__ xb,
    const short* __restrict__ Wqb, const short* __restrict__ Wkb, const short* __restrict__ Wvb,
    const float* __restrict__ bq, const float* __restrict__ bk, const float* __restrict__ bv,
    short* __restrict__ Qh, short* __restrict__ Kh, short* __restrict__ Vt) {
  const int lin = blockIdx.x;
  const int s = ((lin & 7) * 24) + (lin >> 3);
  const int bx = s & 15, by = s >> 4;
  const int z = by >> 2;
  const int m0 = bx << 8, nl0 = (by & 3) << 8;
  extern __shared__ short sm[];
  if (z == 0)      qkv_core<true >(xb, Wqb, bq, Qh, sm, m0, nl0);
  else if (z == 1) qkv_core<true >(xb, Wkb, bk, Kh, sm, m0, nl0);
  else             qkv_core<false>(xb, Wvb, bv, Vt, sm, m0, nl0);
}

// ---------- output projection GEMM: 128x128, R0-verified 2-barrier, fp32 out ----------
__global__ __launch_bounds__(256) void gemm_out(const short* __restrict__ Ab,
                                                const short* __restrict__ Wo,
                                                const float* __restrict__ bo,
                                                float* __restrict__ Cout) {
  const int m0 = blockIdx.x << 7;
  const int n0 = blockIdx.y << 7;
  const int tid = threadIdx.x;
  const int w = tid >> 6, lane = tid & 63;
  const int m15 = lane & 15, quad = lane >> 4;
  const int wr = w >> 1, wc = w & 1;

  __shared__ short As[4096];
  __shared__ short Bs[4096];

  f32x4 acc[4][4];
#pragma unroll
  for (int i = 0; i < 4; ++i)
#pragma unroll
    for (int j = 0; j < 4; ++j) { f32x4 zz = {0.f, 0.f, 0.f, 0.f}; acc[i][j] = zz; }

  const int srow = (w << 5) + (lane >> 2);
  const int scol = (lane & 3) << 3;
  const short* ga0 = Ab + (m0 + srow) * 1024 + scol;
  const short* ga1 = ga0 + 16 * 1024;
  const short* gb0 = Wo + (n0 + srow) * 1024 + scol;
  const short* gb1 = gb0 + 16 * 1024;
  short* la0 = &As[srow * 32 + scol];
  short* la1 = la0 + 512;
  short* lb0 = &Bs[srow * 32 + scol];
  short* lb1 = lb0 + 512;

  for (int kt = 0; kt < 32; ++kt) {
    async16(ga0, la0); async16(ga1, la1);
    async16(gb0, lb0); async16(gb1, lb1);
    ga0 += 32; ga1 += 32; gb0 += 32; gb1 += 32;
    __syncthreads();
    bf16x8 a[4], b[4];
#pragma unroll
    for (int i = 0; i < 4; ++i)
      a[i] = *(const bf16x8*)(&As[((wr << 6) + (i << 4) + m15) * 32 + (quad << 3)]);
#pragma unroll
    for (int j = 0; j < 4; ++j)
      b[j] = *(const bf16x8*)(&Bs[((wc << 6) + (j << 4) + m15) * 32 + (quad << 3)]);
#pragma unroll
    for (int i = 0; i < 4; ++i)
#pragma unroll
      for (int j = 0; j < 4; ++j)
        acc[i][j] = MFMA_BF16(a[i], b[j], acc[i][j]);
    __syncthreads();
  }

#pragma unroll
  for (int j = 0; j < 4; ++j) {
    const int n = n0 + (wc << 6) + (j << 4) + m15;
    const float bb_ = bo[n];
#pragma unroll
    for (int i = 0; i < 4; ++i) {
      const int mb = m0 + (wr << 6) + (i << 4) + (quad << 2);
#pragma unroll
      for (int r = 0; r < 4; ++r)
        Cout[(mb + r) * 1024 + n] = acc[i][j][r] + bb_;
    }
  }
}

// ---------- flash attention, transposed-S, QBLK=128, T15 defer-PV pipeline ----------
// Iter t: STAGE(t+1) | QK[t] | PV[t-1] (pf_prev regs, Vs[(t-1)%3]) | softmax[t].
// PV is independent of QK[t]'s K-latency and softmax's VALU chain -> MFMA/VALU
// overlap. V triple-buffered: write (t+1)%3, read (t-1)%3, hold t%3 (disjoint).
// meanV fused into the PV block via ones-MFMA (o_mv).
__global__ __launch_bounds__(256, 2) void attn_k(const short* __restrict__ Qh,
                                                 const short* __restrict__ Kh,
                                                 const short* __restrict__ Vt,
                                                 const float* __restrict__ gates,
                                                 short* __restrict__ attnb) {
  const int bh = blockIdx.x;
  const int b = bh >> 4, h = bh & 15;
  const int q0 = blockIdx.y << 7;
  const int tid = threadIdx.x;
  const int w = tid >> 6, lane = tid & 63;
  const int m15 = lane & 15, quad = lane >> 4;

  __shared__ short Ks[2][4096];  // [64 k][64 d], 8-short chunks XOR-swizzled by row&7
  __shared__ short Vs[3][4096];  // [64 d][64 t], same swizzle, triple-buffered

  const short* ksrc = Kh + bh * 65536;
  const short* vsrc = Vt + bh * 65536;

  const float sl = gates[b * 2 + 1];

  // hoisted Q B-fragments for both q-groups (loop-invariant)
  const short* qsrcA = Qh + ((bh << 10) + q0 + (w << 4) + m15) * 64;
  const short* qsrcB = qsrcA + 64 * 64;  // +64 q-rows
  const bf16x8 qA0 = *(const bf16x8*)(qsrcA + (quad << 3));
  const bf16x8 qA1 = *(const bf16x8*)(qsrcA + 32 + (quad << 3));
  const bf16x8 qB0 = *(const bf16x8*)(qsrcB + (quad << 3));
  const bf16x8 qB1 = *(const bf16x8*)(qsrcB + 32 + (quad << 3));

  const bf16x8 vone = {0x3F80, 0x3F80, 0x3F80, 0x3F80, 0x3F80, 0x3F80, 0x3F80, 0x3F80};

  const int off0 = tid, off1 = tid + 256;
  const int r0 = off0 >> 3, cb0 = (off0 & 7) ^ (r0 & 7);
  const int r1 = off1 >> 3, cb1 = (off1 & 7) ^ (r1 & 7);

#define STAGE(kv, kb, vb)                                                      \
  do {                                                                         \
    async16(ksrc + (((kv) << 6) + r0) * 64 + (cb0 << 3), &Ks[kb][off0 << 3]);  \
    async16(ksrc + (((kv) << 6) + r1) * 64 + (cb1 << 3), &Ks[kb][off1 << 3]);  \
    async16(vsrc + r0 * 1024 + ((kv) << 6) + (cb0 << 3), &Vs[vb][off0 << 3]);  \
    async16(vsrc + r1 * 1024 + ((kv) << 6) + (cb1 << 3), &Vs[vb][off1 << 3]);  \
  } while (0)

  STAGE(0, 0, 0);

  float lsumA = 0.f, lsumB = 0.f;
  f32x4 oA[4], oB[4], o_mv[4];
#pragma unroll
  for (int jd = 0; jd < 4; ++jd) {
    f32x4 zz = {0.f, 0.f, 0.f, 0.f};
    oA[jd] = zz; oB[jd] = zz; o_mv[jd] = zz;
  }

  const int srcA = ((quad & 1) << 5) + m15;
  const int srcB = srcA + 16;
  const bool selhi = (quad & 2) != 0;

#define BUILD_PF(pf, pk)                                                       \
  do {                                                                         \
    _Pragma("unroll")                                                          \
    for (int Hh = 0; Hh < 2; ++Hh) {                                           \
      uint32_t f[4];                                                           \
      _Pragma("unroll")                                                        \
      for (int rp = 0; rp < 2; ++rp) {                                         \
        uint32_t alo = (uint32_t)__shfl((int)pk[2 * Hh][rp], srcA);            \
        uint32_t ahi = (uint32_t)__shfl((int)pk[2 * Hh + 1][rp], srcA);        \
        uint32_t blo = (uint32_t)__shfl((int)pk[2 * Hh][rp], srcB);            \
        uint32_t bhi = (uint32_t)__shfl((int)pk[2 * Hh + 1][rp], srcB);        \
        f[rp]     = selhi ? ahi : alo;                                         \
        f[2 + rp] = selhi ? bhi : blo;                                         \
      }                                                                        \
      pf[Hh] = *(bf16x8*)f;                                                    \
    }                                                                          \
  } while (0)

// PV over one V tile (Vb) with B-fragments pfa/pfb (prev iter's P)
#define PV_STEP(Vb, pfa, pfb)                                                  \
  do {                                                                         \
    _Pragma("unroll")                                                          \
    for (int jd = 0; jd < 4; ++jd) {                                           \
      const int row = (jd << 4) + m15;                                         \
      const int sw = row & 7;                                                  \
      bf16x8 v0 = *(const bf16x8*)((Vb) + (row << 6) + ((quad ^ sw) << 3));    \
      bf16x8 v1 = *(const bf16x8*)((Vb) + (row << 6) + (((quad + 4) ^ sw) << 3)); \
      oA[jd] = MFMA_BF16(v0, pfa[0], oA[jd]);                                  \
      oA[jd] = MFMA_BF16(v1, pfa[1], oA[jd]);                                  \
      oB[jd] = MFMA_BF16(v0, pfb[0], oB[jd]);                                  \
      oB[jd] = MFMA_BF16(v1, pfb[1], oB[jd]);                                  \
      o_mv[jd] = MFMA_BF16(v0, vone, o_mv[jd]);                                \
      o_mv[jd] = MFMA_BF16(v1, vone, o_mv[jd]);                                \
    }                                                                          \
  } while (0)

  bf16x8 pfpA[2], pfpB[2];
  pfpA[0] = (bf16x8){0,0,0,0,0,0,0,0}; pfpA[1] = pfpA[0];
  pfpB[0] = pfpA[0]; pfpB[1] = pfpA[0];

  for (int kv = 0; kv < 16; ++kv) {
    __syncthreads();  // Ks[kv&1]/Vs[kv%3] landed; prior reads done
    if (kv < 15) STAGE(kv + 1, (kv + 1) & 1, (kv + 1) % 3);
    const short* Kb = &Ks[kv & 1][0];

    // --- QK[kv]: S^T tiles for both q-groups; K frags shared ---
    f32x4 sA[4], sB[4];
#pragma unroll
    for (int s = 0; s < 4; ++s) {
      const int row = (s << 4) + m15;
      const int sw = row & 7;
      bf16x8 a0 = *(const bf16x8*)(Kb + (row << 6) + ((quad ^ sw) << 3));
      bf16x8 a1 = *(const bf16x8*)(Kb + (row << 6) + (((quad + 4) ^ sw) << 3));
      f32x4 zA = {0.f, 0.f, 0.f, 0.f};
      zA = MFMA_BF16(a0, qA0, zA);
      zA = MFMA_BF16(a1, qA1, zA);
      sA[s] = zA;
      f32x4 zB = {0.f, 0.f, 0.f, 0.f};
      zB = MFMA_BF16(a0, qB0, zB);
      zB = MFMA_BF16(a1, qB1, zB);
      sB[s] = zB;
    }

    // --- PV[kv-1]: independent of QK[kv] and of softmax below ---
    if (kv > 0) {
      const short* Vb = &Vs[(kv - 1) % 3][0];
      PV_STEP(Vb, pfpA, pfpB);
    }

    // --- softmax[kv]: lane-local numerators + packed bf16 pairs ---
    uint32_t pkA[4][2], pkB[4][2];
#pragma unroll
    for (int s = 0; s < 4; ++s) {
      float a0 = fexp2(sA[s][0] * sl);
      float a1 = fexp2(sA[s][1] * sl);
      float a2 = fexp2(sA[s][2] * sl);
      float a3 = fexp2(sA[s][3] * sl);
      lsumA += (a0 + a1) + (a2 + a3);
      pkA[s][0] = pack2bf(a0, a1);
      pkA[s][1] = pack2bf(a2, a3);
      float b0 = fexp2(sB[s][0] * sl);
      float b1 = fexp2(sB[s][1] * sl);
      float b2 = fexp2(sB[s][2] * sl);
      float b3 = fexp2(sB[s][3] * sl);
      lsumB += (b0 + b1) + (b2 + b3);
      pkB[s][0] = pack2bf(b0, b1);
      pkB[s][1] = pack2bf(b2, b3);
    }

    bf16x8 pfA[2], pfB[2];
    BUILD_PF(pfA, pkA);
    BUILD_PF(pfB, pkB);
    pfpA[0] = pfA[0]; pfpA[1] = pfA[1];
    pfpB[0] = pfB[0]; pfpB[1] = pfB[1];
  }

  // --- epilogue PV[15]: Vs[15%3=0], staged at kv=14, drained by kv=15 barrier ---
  {
    const short* Vb = &Vs[15 % 3][0];
    PV_STEP(Vb, pfpA, pfpB);
  }
#undef STAGE
#undef BUILD_PF
#undef PV_STEP

  // finish l(q): reduce quad partials
  float lA = lsumA;
  lA += __shfl_xor(lA, 16);
  lA += __shfl_xor(lA, 32);
  float lB = lsumB;
  lB += __shfl_xor(lB, 16);
  lB += __shfl_xor(lB, 32);

  const float cg = gates[b * 2 + 0];
  const float sc0A = cg / lA;
  const float sc0B = cg / lB;
  const float coef = (1.0f - cg) * (1.0f / 1024.0f);  // o_mv holds raw sums over t
  const int qrowA = q0 + (w << 4) + m15;
  short* orowA = attnb + ((b << 10) + qrowA) * 1024 + (h << 6);
  short* orowB = orowA + 64 * 1024;  // qrowB = qrowA + 64
#pragma unroll
  for (int jd = 0; jd < 4; ++jd) {
    uint2 stA;
    stA.x = pack2bf(sc0A * oA[jd][0] + coef * o_mv[jd][0],
                    sc0A * oA[jd][1] + coef * o_mv[jd][1]);
    stA.y = pack2bf(sc0A * oA[jd][2] + coef * o_mv[jd][2],
                    sc0A * oA[jd][3] + coef * o_mv[jd][3]);
    *(uint2*)(orowA + (jd << 4) + (quad << 2)) = stA;
    uint2 stB;
    stB.x = pack2bf(sc0B * oB[jd][0] + coef * o_mv[jd][0],
                    sc0B * oB[jd][1] + coef * o_mv[jd][1]);
    stB.y = pack2bf(sc0B * oB[jd][2] + coef * o_mv[jd][2],
                    sc0B * oB[jd][3] + coef * o_mv[jd][3]);
    *(uint2*)(orowB + (jd << 4) + (quad << 2)) = stB;
  }
}

// ---------- launch ----------
extern "C" void kernel_launch(void* const* d_in, const int* in_sizes, int n_in,
                              void* d_out, int out_size, void* d_ws, size_t ws_size,
                              hipStream_t stream) {
  const float* x   = (const float*)d_in[0];
  const float* Wq  = (const float*)d_in[1];
  const float* bq  = (const float*)d_in[2];
  const float* Wk  = (const float*)d_in[3];
  const float* bk  = (const float*)d_in[4];
  const float* Wv  = (const float*)d_in[5];
  const float* bv  = (const float*)d_in[6];
  const float* Wo  = (const float*)d_in[7];
  const float* bo  = (const float*)d_in[8];
  const float* Wg1 = (const float*)d_in[9];
  const float* bg1 = (const float*)d_in[10];
  const float* Wg2 = (const float*)d_in[11];
  const float* bg2 = (const float*)d_in[12];
  float* out = (float*)d_out;

  char* ws = (char*)d_ws;
  short* xb   = (short*)(ws + 0);          //  8 MB  x bf16 [4096][1024]
  short* Wqb  = (short*)(ws + 8388608);    //  2 MB
  short* Wkb  = (short*)(ws + 10485760);   //  2 MB
  short* Wvb  = (short*)(ws + 12582912);   //  2 MB
  short* Wob  = (short*)(ws + 14680064);   //  2 MB
  short* Qh   = (short*)(ws + 16777216);   //  8 MB  [BH][T][64]
  short* Kh   = (short*)(ws + 25165824);   //  8 MB  [BH][T][64]
  short* Vt   = (short*)(ws + 33554432);   //  8 MB  [BH][64][T]
  short* attb = (short*)(ws + 41943040);   //  8 MB  [4096][1024]
  float* ctx  = (float*)(ws + 50331648);   // 16 KB
  float* gat  = (float*)(ws + 50348032);   // 32 B   [B][{c, scale*log2e}]

  static bool lds_inited = false;
  if (!lds_inited) {
    hipFuncSetAttribute(reinterpret_cast<const void*>(gemm_qkv8),
                        hipFuncAttributeMaxDynamicSharedMemorySize, 131072);
    lds_inited = true;
  }

  prep_k<<<8256, 256, 0, stream>>>(x, Wq, Wk, Wv, Wo, bq,
                                   xb, Wqb, Wkb, Wvb, Wob, ctx);
  gates_fin<<<1, 256, 0, stream>>>(ctx, Wg1, bg1, Wg2, bg2, gat, out + 4194304);

  gemm_qkv8<<<192, 512, 131072, stream>>>(xb, Wqb, Wkb, Wvb, bq, bk, bv,
                                          Qh, Kh, Vt);
  attn_k<<<dim3(64, 8), 256, 0, stream>>>(Qh, Kh, Vt, gat, attb);
  gemm_out<<<dim3(32, 8), 256, 0, stream>>>(attb, Wob, bo, out);
}